// Round 14
// baseline (409.526 us; speedup 1.0000x reference)
//
#include <hip/hip_runtime.h>
#include <hip/hip_bf16.h>

typedef unsigned short u16;
typedef unsigned int u32;
typedef __attribute__((ext_vector_type(4))) float f32x4;
typedef __attribute__((ext_vector_type(8))) short s16x8;

#define B_ 4
#define N_ 2048
#define D_ 2048
#define HEADS_ 16
#define KVH_ 4
#define DH_ 128
#define KVD_ 1024
#define M_ 8192
// SCALE * log2(e): QK^T scores scaled directly into exp2 domain
#define QSCALE2_ 0.12753257518622628f

__device__ __forceinline__ u16 f2bf(float f) {
  u32 u = __builtin_bit_cast(u32, f);
  return (u16)((u + 0x7FFFu + ((u >> 16) & 1u)) >> 16);
}

__device__ __forceinline__ float fexp2(float x) {
#if __has_builtin(__builtin_amdgcn_exp2f)
  return __builtin_amdgcn_exp2f(x);
#else
  return exp2f(x);
#endif
}

__device__ __forceinline__ void gload_lds16(const void* g, void* l) {
  __builtin_amdgcn_global_load_lds(
      (const __attribute__((address_space(1))) u32*)g,
      (__attribute__((address_space(3))) u32*)l, 16, 0, 0);
}

// ---------------- rope tables: cos/sin [2048][64] ----------------
__global__ __launch_bounds__(256)
void rope_tab_k(float* __restrict__ cost, float* __restrict__ sint)
{
  const int idx = blockIdx.x * 256 + threadIdx.x;   // 131072
  const int p = idx >> 6, i = idx & 63;
  const float theta = expf(-(float)i * 0.015625f * 9.210340371976184f); // 10000^(-2i/128)
  float s, c;
  sincosf((float)p * theta, &s, &c);
  cost[idx] = c;
  sint[idx] = s;
}

// ---------------- f32 -> bf16 convert ----------------
__global__ __launch_bounds__(256)
void cvt_bf16_k(const float* __restrict__ s, u16* __restrict__ d, int n)
{
  const int i = (blockIdx.x * 256 + threadIdx.x) * 8;
  if (i >= n) return;
  const f32x4 a = *(const f32x4*)(s + i);
  const f32x4 b = *(const f32x4*)(s + i + 4);
  s16x8 o;
  #pragma unroll
  for (int j = 0; j < 4; ++j) { o[j] = (short)f2bf(a[j]); o[4 + j] = (short)f2bf(b[j]); }
  *(s16x8*)(d + i) = o;
}

// ---------------- RMSNorm: one block per row ----------------
__global__ __launch_bounds__(256)
void rmsnorm_k(const float* __restrict__ x, const float* __restrict__ w, u16* __restrict__ xn)
{
  const int row = blockIdx.x, t = threadIdx.x;
  const float* xr = x + (size_t)row * D_;
  const f32x4 a = *(const f32x4*)(xr + t * 8);
  const f32x4 b = *(const f32x4*)(xr + t * 8 + 4);
  float ss = a[0]*a[0] + a[1]*a[1] + a[2]*a[2] + a[3]*a[3]
           + b[0]*b[0] + b[1]*b[1] + b[2]*b[2] + b[3]*b[3];
  #pragma unroll
  for (int off = 32; off >= 1; off >>= 1) ss += __shfl_xor(ss, off);
  __shared__ float wss[4];
  if ((t & 63) == 0) wss[t >> 6] = ss;
  __syncthreads();
  const float tot = wss[0] + wss[1] + wss[2] + wss[3];
  const float rs = rsqrtf(tot * (1.0f / D_) + 1.1920929e-07f);
  s16x8 o;
  #pragma unroll
  for (int j = 0; j < 4; ++j) {
    o[j]     = (short)f2bf(a[j] * rs * w[t * 8 + j]);
    o[4 + j] = (short)f2bf(b[j] * rs * w[t * 8 + 4 + j]);
  }
  *(s16x8*)(xn + (size_t)row * D_ + t * 8) = o;
}

// ======== 256x128 GEMM, BK=32, burst-staged dbuf pipeline (R13-proven) ========
// Chunk-rotation LDS swizzle: conflicts 1.57e7 -> 0 (R13 verified).
template<int EPI>
__global__ __launch_bounds__(512, 2)
void gemm_p(const u16* __restrict__ A, const u16* __restrict__ Bw,
            void* __restrict__ Cv, void* __restrict__ Cv2,
            const float* __restrict__ bias, const float* __restrict__ bias2,
            const float* __restrict__ cos_t, const float* __restrict__ sin_t)
{
  __shared__ __align__(16) u16 As[2][8192];   // [256][32] chunk-rotated
  __shared__ __align__(16) u16 Bs[2][4096];   // [128][32] chunk-rotated
  const int t = threadIdx.x, w = t >> 6, l = t & 63;
  const int g = l >> 4, lr = l & 15;
  const int wm = w >> 2, wn = w & 3;

  // XCD-aware bijective block swizzle
  const int nbx = gridDim.x;
  const int nb = nbx * gridDim.y;
  const int flat = blockIdx.y * nbx + blockIdx.x;
  const int swz = (flat & 7) * (nb >> 3) + (flat >> 3);
  const int row0 = (swz / nbx) * 256, col0 = (swz % nbx) * 128;

  const int NT = 64;   // 2048 / 32

  const int srow = w * 16 + (l >> 2);
  // pre-rotated source column (both-sides rule; intra-64B perm)
  const int scol = ((((l & 3) - ((l >> 3) & 3)) & 3)) * 8;
  const u16* gA = A + (size_t)(row0 + srow) * 2048 + scol;
  const u16* gB = Bw + (size_t)(col0 + srow) * 2048 + scol;

  // loop-invariant rotated read chunk
  const int rc = (g + ((lr >> 1) & 3)) & 3;

  f32x4 acc[8][2] = {};

  auto stage_tile = [&](int kt2, int pb) {
    gload_lds16(gA + (size_t)kt2 * 32, &As[pb][(w * 16) * 32]);
    gload_lds16(gA + (size_t)128 * 2048 + kt2 * 32, &As[pb][(128 + w * 16) * 32]);
    gload_lds16(gB + (size_t)kt2 * 32, &Bs[pb][(w * 16) * 32]);
  };

  stage_tile(0, 0);

  for (int kt = 0; kt < NT; ++kt) {
    const int p = kt & 1;
    if (kt + 1 < NT) {
      stage_tile(kt + 1, p ^ 1);
      asm volatile("s_waitcnt vmcnt(3)" ::: "memory");  // tile kt resident; kt+1 in flight
    } else {
      asm volatile("s_waitcnt vmcnt(0)" ::: "memory");
    }
    __builtin_amdgcn_s_barrier();

    s16x8 bf[2], af[8];
    #pragma unroll
    for (int nf = 0; nf < 2; ++nf)
      bf[nf] = *(const s16x8*)(&Bs[p][(wn * 32 + nf * 16 + lr) * 32 + rc * 8]);
    #pragma unroll
    for (int mf = 0; mf < 8; ++mf)
      af[mf] = *(const s16x8*)(&As[p][(wm * 128 + mf * 16 + lr) * 32 + rc * 8]);

    __builtin_amdgcn_s_setprio(1);
    #pragma unroll
    for (int mf = 0; mf < 8; ++mf)
      #pragma unroll
      for (int nf = 0; nf < 2; ++nf)
        acc[mf][nf] = __builtin_amdgcn_mfma_f32_16x16x32_bf16(af[mf], bf[nf], acc[mf][nf], 0, 0, 0);
    __builtin_amdgcn_s_setprio(0);
    __builtin_amdgcn_sched_barrier(0);
    __builtin_amdgcn_s_barrier();   // protect buf p from next iter's staging
  }

  // ---- epilogue ----
  #pragma unroll
  for (int mf = 0; mf < 8; ++mf) {
    #pragma unroll
    for (int nf = 0; nf < 2; ++nf) {
      const int cc = col0 + wn * 32 + nf * 16 + lr;
      const float bv = (EPI == 4 && cc >= 2048) ? bias2[cc - 2048] : bias[cc];
      #pragma unroll
      for (int j = 0; j < 4; ++j) {
        const int rr = row0 + wm * 128 + mf * 16 + g * 4 + j;
        float v = acc[mf][nf][j] + bv;
        if (EPI == 0) {
          ((float*)Cv)[(size_t)rr * 2048 + cc] = v;
        } else {
          const int pos = rr & (N_ - 1);
          const float pv = __shfl_xor(v, 1);
          if (cc < 2048) {        // Q: RoPE on all cols
            const int d = cc & (DH_ - 1);
            const float c = cos_t[pos * 64 + (d >> 1)];
            const float s = sin_t[pos * 64 + (d >> 1)];
            const float o = (cc & 1) ? fmaf(v, c, pv * s) : fmaf(v, c, -pv * s);
            ((u16*)Cv)[(size_t)rr * 2048 + cc] = f2bf(o);
          } else {                // KV: RoPE on K half only
            const int ccc = cc - 2048;
            const int dm = ccc & 255;
            float o = v;
            if (dm < DH_) {
              const float c = cos_t[pos * 64 + (dm >> 1)];
              const float s = sin_t[pos * 64 + (dm >> 1)];
              o = (dm & 1) ? fmaf(v, c, pv * s) : fmaf(v, c, -pv * s);
            }
            ((u16*)Cv2)[(size_t)rr * 1024 + ccc] = f2bf(o);
          }
        }
      }
    }
  }
}

// ---------------- V transpose: kv[.., kvh*256+128+d] -> vt[b][kvh][d][pos] ----------------
__global__ __launch_bounds__(256)
void vtrans_k(const u16* __restrict__ kvb, u16* __restrict__ vt)
{
  __shared__ u16 tile[64][65];
  const int z = blockIdx.z, b = z >> 2, kh = z & 3;
  const int p0 = blockIdx.x * 64, d0 = blockIdx.y * 64;
  const int t = threadIdx.x;
  #pragma unroll
  for (int r = 0; r < 2; ++r) {
    const int pl = r * 32 + (t >> 3), dl = (t & 7) * 8;
    const s16x8 v = *(const s16x8*)(kvb + (size_t)(b * N_ + p0 + pl) * KVD_ + kh * 256 + 128 + d0 + dl);
    #pragma unroll
    for (int jj = 0; jj < 8; ++jj) tile[pl][dl + jj] = (u16)v[jj];
  }
  __syncthreads();
  #pragma unroll
  for (int r = 0; r < 2; ++r) {
    const int dl = r * 32 + (t >> 3), pl = (t & 7) * 8;
    s16x8 o;
    #pragma unroll
    for (int jj = 0; jj < 8; ++jj) o[jj] = (short)tile[pl + jj][dl];
    *(s16x8*)(vt + ((size_t)(z * DH_ + d0 + dl)) * N_ + p0 + pl) = o;
  }
}

// ---------------- flash attention (causal, GQA 4:1) ----------------
// R14: repackage R12's proven per-wave shape (32 q-rows in two 16-row groups,
// KVBLK=64 -- the 2x LDS-intensity win) into 4-WAVE blocks for 2 blocks/CU.
// R8-R13 diag: 8-wave attn blocks need ~192 total regs/wave x16 waves > budget
// -> permanently 1 block/CU -> every barrier idles the whole CU. 4-wave
// blocks: 8 waves/CU x ~192 regs fits; LDS 80KB (K 32 + V 32 + Ps 16) ->
// exactly 2 blocks/CU; two independent barrier groups give m114 cross-block
// overlap. QBLK=128 (4 waves x 32 rows), 16 q-tiles, fold fi & 15-fi ->
// uniform 34 iters/block, grid (8,16,4)=512 = 2/CU. (R10's 4-wave failure
// conflated KVBLK=32 + tail-heavy grid; this isolates the packaging.)
__global__ __launch_bounds__(256, 2)
void attn_k(const u16* __restrict__ q, const u16* __restrict__ kvb,
            const u16* __restrict__ vt, u16* __restrict__ out)
{
  const int fi = blockIdx.x, h = blockIdx.y, b = blockIdx.z;
  const int kh = h >> 2;
  const int t = threadIdx.x, w = t >> 6, lane = t & 63;
  const int g = lane >> 4, lr = lane & 15;

  __shared__ __align__(16) u16 Ks[2][64 * 128];   // 32KB [kv][d] swizzled, dbuf
  __shared__ __align__(16) u16 Vs[2][128 * 64];   // 32KB [d][kv] swizzled, dbuf
  __shared__ __align__(16) u16 Ps[4][32 * 64];    // 16KB per-wave [q32][kv64] swizzled

  const u16* kbase = kvb + (size_t)b * (N_ * KVD_) + kh * 256;
  const u16* vbase = vt + (size_t)((b * KVH_ + kh) * DH_) * N_;

  int cur = 0;

  // staging: K tile 16KB = 16 chunks of 1KB (4 rows x 256B); V tile 16KB =
  // 16 chunks (8 rows x 128B). Wave w stages chunks 4w..4w+3 of both.
  // Linear LDS dest; global source column pre-swizzled (rule 21):
  //   K[r][slot s] at LDS byte r*256 + (s^(r&7))*16
  //   V[d][slot s] at LDS byte d*128 + (s^(d&7))*16
  auto issue = [&](int kt, int buf) {
    #pragma unroll
    for (int i = 0; i < 4; ++i) {
      const int c = 4 * w + i;
      const int kr = 4 * c + (lane >> 4);
      const int ksw = (lane & 15) ^ (kr & 7);
      gload_lds16(kbase + (size_t)(kt * 64 + kr) * KVD_ + ksw * 8, &Ks[buf][c * 512]);
      const int vd = 8 * c + (lane >> 3);
      const int vsw = (lane & 7) ^ (vd & 7);
      gload_lds16(vbase + (size_t)vd * N_ + kt * 64 + vsw * 8, &Vs[buf][c * 512]);
    }
  };

  auto run_qtile = [&](int qi, int nkt, bool chain) {
    const int qrow0 = qi * 128 + w * 32;       // wave-uniform; rows qrow0..qrow0+31
    const int td = (qrow0 + 31) >> 6;          // diagonal kv-tile (only tile that masks)
    s16x8 qf[2][4];
    #pragma unroll
    for (int r = 0; r < 2; ++r) {
      const u16* qp = q + (size_t)(b * N_ + qrow0 + r * 16 + lr) * D_ + h * DH_;
      #pragma unroll
      for (int ks = 0; ks < 4; ++ks) qf[r][ks] = *(const s16x8*)(qp + ks * 32 + g * 8);
    }
    f32x4 o_acc[2][8] = {};
    float m_j[2][4], l_j[2][4];
    #pragma unroll
    for (int r = 0; r < 2; ++r)
      #pragma unroll
      for (int j = 0; j < 4; ++j) { m_j[r][j] = -1e30f; l_j[r][j] = 0.0f; }

    for (int kt = 0; kt < nkt; ++kt) {
      // compiler drains prev-iter issues (vmcnt(0)) before this barrier:
      // tile kt resident after it
      __syncthreads();
      if (kt + 1 < nkt)      issue(kt + 1, cur ^ 1);
      else if (chain)        issue(0, cur ^ 1);   // preload next q-tile's tile 0

      if (kt <= td) {   // wave-uniform causal skip
        const u16* Kc = &Ks[cur][0];
        const u16* Vc = &Vs[cur][0];

        // S = Q K^T : K frag read ONCE, used by both row groups (2x intensity)
        f32x4 sf[2][4] = {};
        __builtin_amdgcn_s_setprio(1);
        #pragma unroll
        for (int ks = 0; ks < 4; ++ks) {
          #pragma unroll
          for (int kvf = 0; kvf < 4; ++kvf) {
            const int kvr = kvf * 16 + lr;
            const int ba = (kvr * 256 + ks * 64 + g * 16) ^ ((kvr & 7) << 4);
            const s16x8 kf = *(const s16x8*)((const char*)Kc + ba);
            sf[0][kvf] = __builtin_amdgcn_mfma_f32_16x16x32_bf16(qf[0][ks], kf, sf[0][kvf], 0, 0, 0);
            sf[1][kvf] = __builtin_amdgcn_mfma_f32_16x16x32_bf16(qf[1][ks], kf, sf[1][kvf], 0, 0, 0);
          }
        }
        __builtin_amdgcn_s_setprio(0);

        // scale into exp2 domain; mask only on the diagonal tile
        const bool need_mask = (kt == td);
        float pmax[2][4];
        #pragma unroll
        for (int r = 0; r < 2; ++r) {
          #pragma unroll
          for (int j = 0; j < 4; ++j) {
            float mx = -1e30f;
            #pragma unroll
            for (int kvf = 0; kvf < 4; ++kvf) {
              float sv = sf[r][kvf][j] * QSCALE2_;
              if (need_mask) {
                const int kj = kt * 64 + kvf * 16 + lr;
                const int qi_row = qrow0 + r * 16 + g * 4 + j;
                if (kj > qi_row) sv = -1e30f;
              }
              sf[r][kvf][j] = sv;
              mx = fmaxf(mx, sv);
            }
            mx = fmaxf(mx, __shfl_xor(mx, 1));
            mx = fmaxf(mx, __shfl_xor(mx, 2));
            mx = fmaxf(mx, __shfl_xor(mx, 4));
            mx = fmaxf(mx, __shfl_xor(mx, 8));
            pmax[r][j] = mx;
          }
        }

        // defer-max: full rescale only when the running max grew by > 8
        float needv = -1e30f;
        #pragma unroll
        for (int r = 0; r < 2; ++r)
          #pragma unroll
          for (int j = 0; j < 4; ++j) needv = fmaxf(needv, pmax[r][j] - m_j[r][j]);
        if (__any(needv > 8.0f)) {
          #pragma unroll
          for (int r = 0; r < 2; ++r)
            #pragma unroll
            for (int j = 0; j < 4; ++j) {
              const float mn = fmaxf(m_j[r][j], pmax[r][j]);
              const float pf = fexp2(m_j[r][j] - mn);
              m_j[r][j] = mn;
              l_j[r][j] *= pf;
              #pragma unroll
              for (int df = 0; df < 8; ++df) o_acc[r][df][j] *= pf;
            }
        }

        // P = exp2(S - m); per-lane partial l; truncating bf16 store
        #pragma unroll
        for (int r = 0; r < 2; ++r) {
          #pragma unroll
          for (int j = 0; j < 4; ++j) {
            float lacc = 0.0f;
            #pragma unroll
            for (int kvf = 0; kvf < 4; ++kvf) {
              const float p = fexp2(sf[r][kvf][j] - m_j[r][j]);
              lacc += p;
              const int rq = r * 16 + g * 4 + j, ck = kvf * 16 + lr;
              const int ba = (rq * 128 + ck * 2) ^ ((rq & 7) << 4);
              *(u16*)((char*)&Ps[w][0] + ba) = (u16)(__builtin_bit_cast(u32, p) >> 16);
            }
            l_j[r][j] += lacc;
          }
        }

        // O += P V : V frag read ONCE, used by both row groups
        __builtin_amdgcn_s_setprio(1);
        #pragma unroll
        for (int kk = 0; kk < 2; ++kk) {
          s16x8 pf[2];
          #pragma unroll
          for (int r = 0; r < 2; ++r) {
            const int prow = r * 16 + lr;
            const int bap = (prow * 128 + kk * 64 + g * 16) ^ ((prow & 7) << 4);
            pf[r] = *(const s16x8*)((const char*)&Ps[w][0] + bap);
          }
          #pragma unroll
          for (int df = 0; df < 8; ++df) {
            const int dd = df * 16 + lr;
            const int bav = (dd * 128 + kk * 64 + g * 16) ^ ((dd & 7) << 4);
            const s16x8 vf = *(const s16x8*)((const char*)Vc + bav);
            o_acc[0][df] = __builtin_amdgcn_mfma_f32_16x16x32_bf16(pf[0], vf, o_acc[0][df], 0, 0, 0);
            o_acc[1][df] = __builtin_amdgcn_mfma_f32_16x16x32_bf16(pf[1], vf, o_acc[1][df], 0, 0, 0);
          }
        }
        __builtin_amdgcn_s_setprio(0);
      }
      cur ^= 1;
    }

    #pragma unroll
    for (int r = 0; r < 2; ++r) {
      float inv_l[4];
      #pragma unroll
      for (int j = 0; j < 4; ++j) {
        float s4 = l_j[r][j];
        s4 += __shfl_xor(s4, 1);
        s4 += __shfl_xor(s4, 2);
        s4 += __shfl_xor(s4, 4);
        s4 += __shfl_xor(s4, 8);
        inv_l[j] = 1.0f / s4;
      }
      u16* op = out + (size_t)(b * N_ + qrow0 + r * 16) * D_ + h * DH_;
      #pragma unroll
      for (int df = 0; df < 8; ++df)
        #pragma unroll
        for (int j = 0; j < 4; ++j)
          op[(size_t)(g * 4 + j) * D_ + df * 16 + lr] = f2bf(o_acc[r][df][j] * inv_l[j]);
    }
  };

  const int qlo = fi, qhi = 15 - fi;      // fold: every block runs 34 iterations
  issue(0, 0);
  run_qtile(qlo, 2 * qlo + 2, true);
  run_qtile(qhi, 2 * qhi + 2, false);
}

extern "C" void kernel_launch(void* const* d_in, const int* in_sizes, int n_in,
                              void* d_out, int out_size, void* d_ws, size_t ws_size,
                              hipStream_t stream) {
  const float* x      = (const float*)d_in[0];
  const float* normw  = (const float*)d_in[1];
  const float* qw     = (const float*)d_in[2];
  const float* qbias  = (const float*)d_in[3];
  const float* kvw    = (const float*)d_in[4];
  const float* kvbias = (const float*)d_in[5];
  const float* wow    = (const float*)d_in[6];
  const float* wob    = (const float*)d_in[7];
  // d_in[8] = kv_cache (unused: pos=0), d_in[9] = pos (0)
  float* out = (float*)d_out;

  char* ws = (char*)d_ws;
  u16* xn    = (u16*)(ws + 0);          // 33.5 MB (reused as attn output)
  u16* dq    = (u16*)(ws + 33554432);   // 33.5 MB
  u16* dkv   = (u16*)(ws + 67108864);   // 16.8 MB
  u16* dvt   = (u16*)(ws + 83886080);   //  8.4 MB
  u16* wqkv  = (u16*)(ws + 92274688);   // 12.6 MB: qw bf16 [2048 rows] then kvw bf16 [1024 rows]
  u16* wowb  = (u16*)(ws + 104857600);  //  8.4 MB
  float* cost = (float*)(ws + 113246208); // 0.5 MB
  float* sint = (float*)(ws + 113770496); // 0.5 MB

  rope_tab_k<<<512, 256, 0, stream>>>(cost, sint);
  cvt_bf16_k<<<2048, 256, 0, stream>>>(qw, wqkv, 2048 * 2048);
  cvt_bf16_k<<<1024, 256, 0, stream>>>(kvw, wqkv + 2048 * 2048, 1024 * 2048);
  cvt_bf16_k<<<2048, 256, 0, stream>>>(wow, wowb, 2048 * 2048);
  rmsnorm_k<<<8192, 256, 0, stream>>>(x, normw, xn);
  gemm_p<4><<<dim3(24, 32), 512, 0, stream>>>(xn, wqkv, (void*)dq, (void*)dkv,
                                              qbias, kvbias, cost, sint);
  vtrans_k<<<dim3(32, 2, 16), 256, 0, stream>>>(dkv, dvt);
  attn_k<<<dim3(8, 16, 4), 256, 0, stream>>>(dq, dkv, dvt, xn);
  gemm_p<0><<<dim3(16, 32), 512, 0, stream>>>(xn, wowb, (void*)out, nullptr,
                                              wob, nullptr, nullptr, nullptr);
}

// Round 15
// 397.296 us; speedup vs baseline: 1.0308x; 1.0308x over previous
//
#include <hip/hip_runtime.h>
#include <hip/hip_bf16.h>

typedef unsigned short u16;
typedef unsigned int u32;
typedef __attribute__((ext_vector_type(4))) float f32x4;
typedef __attribute__((ext_vector_type(8))) short s16x8;

#define B_ 4
#define N_ 2048
#define D_ 2048
#define HEADS_ 16
#define KVH_ 4
#define DH_ 128
#define KVD_ 1024
#define M_ 8192
// SCALE * log2(e): QK^T scores scaled directly into exp2 domain
#define QSCALE2_ 0.12753257518622628f

__device__ __forceinline__ u16 f2bf(float f) {
  u32 u = __builtin_bit_cast(u32, f);
  return (u16)((u + 0x7FFFu + ((u >> 16) & 1u)) >> 16);
}

__device__ __forceinline__ float fexp2(float x) {
#if __has_builtin(__builtin_amdgcn_exp2f)
  return __builtin_amdgcn_exp2f(x);
#else
  return exp2f(x);
#endif
}

__device__ __forceinline__ void gload_lds16(const void* g, void* l) {
  __builtin_amdgcn_global_load_lds(
      (const __attribute__((address_space(1))) u32*)g,
      (__attribute__((address_space(3))) u32*)l, 16, 0, 0);
}

// ---------------- rope tables: cos/sin [2048][64] ----------------
__global__ __launch_bounds__(256)
void rope_tab_k(float* __restrict__ cost, float* __restrict__ sint)
{
  const int idx = blockIdx.x * 256 + threadIdx.x;   // 131072
  const int p = idx >> 6, i = idx & 63;
  const float theta = expf(-(float)i * 0.015625f * 9.210340371976184f); // 10000^(-2i/128)
  float s, c;
  sincosf((float)p * theta, &s, &c);
  cost[idx] = c;
  sint[idx] = s;
}

// ---------------- f32 -> bf16 convert ----------------
__global__ __launch_bounds__(256)
void cvt_bf16_k(const float* __restrict__ s, u16* __restrict__ d, int n)
{
  const int i = (blockIdx.x * 256 + threadIdx.x) * 8;
  if (i >= n) return;
  const f32x4 a = *(const f32x4*)(s + i);
  const f32x4 b = *(const f32x4*)(s + i + 4);
  s16x8 o;
  #pragma unroll
  for (int j = 0; j < 4; ++j) { o[j] = (short)f2bf(a[j]); o[4 + j] = (short)f2bf(b[j]); }
  *(s16x8*)(d + i) = o;
}

// ---------------- RMSNorm: one block per row ----------------
__global__ __launch_bounds__(256)
void rmsnorm_k(const float* __restrict__ x, const float* __restrict__ w, u16* __restrict__ xn)
{
  const int row = blockIdx.x, t = threadIdx.x;
  const float* xr = x + (size_t)row * D_;
  const f32x4 a = *(const f32x4*)(xr + t * 8);
  const f32x4 b = *(const f32x4*)(xr + t * 8 + 4);
  float ss = a[0]*a[0] + a[1]*a[1] + a[2]*a[2] + a[3]*a[3]
           + b[0]*b[0] + b[1]*b[1] + b[2]*b[2] + b[3]*b[3];
  #pragma unroll
  for (int off = 32; off >= 1; off >>= 1) ss += __shfl_xor(ss, off);
  __shared__ float wss[4];
  if ((t & 63) == 0) wss[t >> 6] = ss;
  __syncthreads();
  const float tot = wss[0] + wss[1] + wss[2] + wss[3];
  const float rs = rsqrtf(tot * (1.0f / D_) + 1.1920929e-07f);
  s16x8 o;
  #pragma unroll
  for (int j = 0; j < 4; ++j) {
    o[j]     = (short)f2bf(a[j] * rs * w[t * 8 + j]);
    o[4 + j] = (short)f2bf(b[j] * rs * w[t * 8 + 4 + j]);
  }
  *(s16x8*)(xn + (size_t)row * D_ + t * 8) = o;
}

// ======== 256x128 GEMM, BK=32, burst-staged dbuf pipeline (R13-proven) ========
// Chunk-rotation LDS swizzle: conflicts 1.57e7 -> 0 (R13 verified).
// R15: EPI4's V-half (dm>=128) now written DIRECTLY TRANSPOSED to dvt
// ([b][kvh][d][pos]) as one packed 8B store per fragment (4 consecutive pos,
// 8B-aligned; 256-row tiles never cross a batch boundary since 2048/256=8).
// This eliminates the separate vtrans kernel (16MB read + 8MB write).
template<int EPI>
__global__ __launch_bounds__(512, 2)
void gemm_p(const u16* __restrict__ A, const u16* __restrict__ Bw,
            void* __restrict__ Cv, void* __restrict__ Cv2, u16* __restrict__ Vt,
            const float* __restrict__ bias, const float* __restrict__ bias2,
            const float* __restrict__ cos_t, const float* __restrict__ sin_t)
{
  __shared__ __align__(16) u16 As[2][8192];   // [256][32] chunk-rotated
  __shared__ __align__(16) u16 Bs[2][4096];   // [128][32] chunk-rotated
  const int t = threadIdx.x, w = t >> 6, l = t & 63;
  const int g = l >> 4, lr = l & 15;
  const int wm = w >> 2, wn = w & 3;

  // XCD-aware bijective block swizzle
  const int nbx = gridDim.x;
  const int nb = nbx * gridDim.y;
  const int flat = blockIdx.y * nbx + blockIdx.x;
  const int swz = (flat & 7) * (nb >> 3) + (flat >> 3);
  const int row0 = (swz / nbx) * 256, col0 = (swz % nbx) * 128;

  const int NT = 64;   // 2048 / 32

  const int srow = w * 16 + (l >> 2);
  // pre-rotated source column (both-sides rule; intra-64B perm)
  const int scol = ((((l & 3) - ((l >> 3) & 3)) & 3)) * 8;
  const u16* gA = A + (size_t)(row0 + srow) * 2048 + scol;
  const u16* gB = Bw + (size_t)(col0 + srow) * 2048 + scol;

  // loop-invariant rotated read chunk
  const int rc = (g + ((lr >> 1) & 3)) & 3;

  f32x4 acc[8][2] = {};

  auto stage_tile = [&](int kt2, int pb) {
    gload_lds16(gA + (size_t)kt2 * 32, &As[pb][(w * 16) * 32]);
    gload_lds16(gA + (size_t)128 * 2048 + kt2 * 32, &As[pb][(128 + w * 16) * 32]);
    gload_lds16(gB + (size_t)kt2 * 32, &Bs[pb][(w * 16) * 32]);
  };

  stage_tile(0, 0);

  for (int kt = 0; kt < NT; ++kt) {
    const int p = kt & 1;
    if (kt + 1 < NT) {
      stage_tile(kt + 1, p ^ 1);
      asm volatile("s_waitcnt vmcnt(3)" ::: "memory");  // tile kt resident; kt+1 in flight
    } else {
      asm volatile("s_waitcnt vmcnt(0)" ::: "memory");
    }
    __builtin_amdgcn_s_barrier();

    s16x8 bf[2], af[8];
    #pragma unroll
    for (int nf = 0; nf < 2; ++nf)
      bf[nf] = *(const s16x8*)(&Bs[p][(wn * 32 + nf * 16 + lr) * 32 + rc * 8]);
    #pragma unroll
    for (int mf = 0; mf < 8; ++mf)
      af[mf] = *(const s16x8*)(&As[p][(wm * 128 + mf * 16 + lr) * 32 + rc * 8]);

    __builtin_amdgcn_s_setprio(1);
    #pragma unroll
    for (int mf = 0; mf < 8; ++mf)
      #pragma unroll
      for (int nf = 0; nf < 2; ++nf)
        acc[mf][nf] = __builtin_amdgcn_mfma_f32_16x16x32_bf16(af[mf], bf[nf], acc[mf][nf], 0, 0, 0);
    __builtin_amdgcn_s_setprio(0);
    __builtin_amdgcn_sched_barrier(0);
    __builtin_amdgcn_s_barrier();   // protect buf p from next iter's staging
  }

  // ---- epilogue ----
  #pragma unroll
  for (int mf = 0; mf < 8; ++mf) {
    #pragma unroll
    for (int nf = 0; nf < 2; ++nf) {
      const int cc = col0 + wn * 32 + nf * 16 + lr;
      const float bv = (EPI == 4 && cc >= 2048) ? bias2[cc - 2048] : bias[cc];
      const int rr0 = row0 + wm * 128 + mf * 16 + g * 4;
      if (EPI == 4 && cc >= 2048 && ((cc - 2048) & 255) >= 128) {
        // V: bias + packed transpose store to dvt[b][kvh][d][pos]
        const int ccc = cc - 2048;
        const int kh2 = ccc >> 8, d = (ccc & 255) - 128;
        u32 lo, hi;
        {
          const u16 p0 = f2bf(acc[mf][nf][0] + bv);
          const u16 p1 = f2bf(acc[mf][nf][1] + bv);
          const u16 p2 = f2bf(acc[mf][nf][2] + bv);
          const u16 p3 = f2bf(acc[mf][nf][3] + bv);
          lo = (u32)p0 | ((u32)p1 << 16);
          hi = (u32)p2 | ((u32)p3 << 16);
        }
        const int bb = rr0 >> 11, pos0 = rr0 & 2047;
        u32* dst = (u32*)(Vt + ((size_t)((bb * KVH_ + kh2) * DH_ + d)) * 2048 + pos0);
        dst[0] = lo;
        dst[1] = hi;
      } else {
        #pragma unroll
        for (int j = 0; j < 4; ++j) {
          const int rr = rr0 + j;
          float v = acc[mf][nf][j] + bv;
          if (EPI == 0) {
            ((float*)Cv)[(size_t)rr * 2048 + cc] = v;
          } else {
            const int pos = rr & (N_ - 1);
            const float pv = __shfl_xor(v, 1);
            if (cc < 2048) {        // Q: RoPE on all cols
              const int d = cc & (DH_ - 1);
              const float c = cos_t[pos * 64 + (d >> 1)];
              const float s = sin_t[pos * 64 + (d >> 1)];
              const float o = (cc & 1) ? fmaf(v, c, pv * s) : fmaf(v, c, -pv * s);
              ((u16*)Cv)[(size_t)rr * 2048 + cc] = f2bf(o);
            } else {                // K half: RoPE
              const int ccc = cc - 2048;
              const int dm = ccc & 255;
              const float c = cos_t[pos * 64 + (dm >> 1)];
              const float s = sin_t[pos * 64 + (dm >> 1)];
              const float o = (dm & 1) ? fmaf(v, c, pv * s) : fmaf(v, c, -pv * s);
              ((u16*)Cv2)[(size_t)rr * 1024 + ccc] = f2bf(o);
            }
          }
        }
      }
    }
  }
}

// ---------------- flash attention (causal, GQA 4:1) ----------------
// R12/R13-proven BEST (183us): 8 waves, 32 q-rows/wave (two 16-row groups
// sharing every K/V fragment -- the 2x LDS-intensity win), QBLK=256,
// fold fi & 7-fi -> 36 iters/block, grid (4,16,4)=256 = 1 round.
// R14's 4-wave repackage was WORSE (occupancy is register-bound at 2
// waves/SIMD either way; doubled staging overhead) -- reverted.
__global__ __launch_bounds__(512, 1)
void attn_k(const u16* __restrict__ q, const u16* __restrict__ kvb,
            const u16* __restrict__ vt, u16* __restrict__ out)
{
  const int fi = blockIdx.x, h = blockIdx.y, b = blockIdx.z;
  const int kh = h >> 2;
  const int t = threadIdx.x, w = t >> 6, lane = t & 63;
  const int g = lane >> 4, lr = lane & 15;

  __shared__ __align__(16) u16 Ks[2][64 * 128];   // 32KB [kv][d] swizzled, dbuf
  __shared__ __align__(16) u16 Vs[2][128 * 64];   // 32KB [d][kv] swizzled, dbuf
  __shared__ __align__(16) u16 Ps[8][32 * 64];    // 32KB per-wave [q32][kv64] swizzled

  const int kc = 2 * w;
  const int kr0 = kc * 4 + (lane >> 4);
  const int ksw0 = (lane & 15) ^ (kr0 & 7);
  const int kr1 = kr0 + 4;
  const int ksw1 = (lane & 15) ^ (kr1 & 7);
  const int vd0 = kc * 8 + (lane >> 3);
  const int vsw0 = (lane & 7) ^ (vd0 & 7);
  const int vd1 = vd0 + 8;
  const int vsw1 = (lane & 7) ^ (vd1 & 7);

  const u16* kbase = kvb + (size_t)b * (N_ * KVD_) + kh * 256;
  const u16* vbase = vt + (size_t)((b * KVH_ + kh) * DH_) * N_;

  int cur = 0;

  auto issue = [&](int kt, int buf) {
    gload_lds16(kbase + (size_t)(kt * 64 + kr0) * KVD_ + ksw0 * 8, &Ks[buf][kc * 512]);
    gload_lds16(kbase + (size_t)(kt * 64 + kr1) * KVD_ + ksw1 * 8, &Ks[buf][(kc + 1) * 512]);
    gload_lds16(vbase + (size_t)vd0 * N_ + kt * 64 + vsw0 * 8, &Vs[buf][kc * 512]);
    gload_lds16(vbase + (size_t)vd1 * N_ + kt * 64 + vsw1 * 8, &Vs[buf][(kc + 1) * 512]);
  };

  auto run_qtile = [&](int qi, int nkt, bool chain) {
    const int qrow0 = qi * 256 + w * 32;       // wave-uniform; rows qrow0..qrow0+31
    const int td = (qrow0 + 31) >> 6;          // diagonal kv-tile (only tile that masks)
    s16x8 qf[2][4];
    #pragma unroll
    for (int r = 0; r < 2; ++r) {
      const u16* qp = q + (size_t)(b * N_ + qrow0 + r * 16 + lr) * D_ + h * DH_;
      #pragma unroll
      for (int ks = 0; ks < 4; ++ks) qf[r][ks] = *(const s16x8*)(qp + ks * 32 + g * 8);
    }
    f32x4 o_acc[2][8] = {};
    float m_j[2][4], l_j[2][4];
    #pragma unroll
    for (int r = 0; r < 2; ++r)
      #pragma unroll
      for (int j = 0; j < 4; ++j) { m_j[r][j] = -1e30f; l_j[r][j] = 0.0f; }

    for (int kt = 0; kt < nkt; ++kt) {
      // compiler drains prev-iter issues (vmcnt(0)) before this barrier:
      // tile kt resident after it
      __syncthreads();
      if (kt + 1 < nkt)      issue(kt + 1, cur ^ 1);
      else if (chain)        issue(0, cur ^ 1);   // preload next q-tile's tile 0

      if (kt <= td) {   // wave-uniform causal skip
        const u16* Kc = &Ks[cur][0];
        const u16* Vc = &Vs[cur][0];

        // S = Q K^T : K frag read ONCE, used by both row groups (2x intensity)
        f32x4 sf[2][4] = {};
        __builtin_amdgcn_s_setprio(1);
        #pragma unroll
        for (int ks = 0; ks < 4; ++ks) {
          #pragma unroll
          for (int kvf = 0; kvf < 4; ++kvf) {
            const int kvr = kvf * 16 + lr;
            const int ba = (kvr * 256 + ks * 64 + g * 16) ^ ((kvr & 7) << 4);
            const s16x8 kf = *(const s16x8*)((const char*)Kc + ba);
            sf[0][kvf] = __builtin_amdgcn_mfma_f32_16x16x32_bf16(qf[0][ks], kf, sf[0][kvf], 0, 0, 0);
            sf[1][kvf] = __builtin_amdgcn_mfma_f32_16x16x32_bf16(qf[1][ks], kf, sf[1][kvf], 0, 0, 0);
          }
        }
        __builtin_amdgcn_s_setprio(0);

        // scale into exp2 domain; mask only on the diagonal tile
        const bool need_mask = (kt == td);
        float pmax[2][4];
        #pragma unroll
        for (int r = 0; r < 2; ++r) {
          #pragma unroll
          for (int j = 0; j < 4; ++j) {
            float mx = -1e30f;
            #pragma unroll
            for (int kvf = 0; kvf < 4; ++kvf) {
              float sv = sf[r][kvf][j] * QSCALE2_;
              if (need_mask) {
                const int kj = kt * 64 + kvf * 16 + lr;
                const int qi_row = qrow0 + r * 16 + g * 4 + j;
                if (kj > qi_row) sv = -1e30f;
              }
              sf[r][kvf][j] = sv;
              mx = fmaxf(mx, sv);
            }
            mx = fmaxf(mx, __shfl_xor(mx, 1));
            mx = fmaxf(mx, __shfl_xor(mx, 2));
            mx = fmaxf(mx, __shfl_xor(mx, 4));
            mx = fmaxf(mx, __shfl_xor(mx, 8));
            pmax[r][j] = mx;
          }
        }

        // defer-max: full rescale only when the running max grew by > 8
        float needv = -1e30f;
        #pragma unroll
        for (int r = 0; r < 2; ++r)
          #pragma unroll
          for (int j = 0; j < 4; ++j) needv = fmaxf(needv, pmax[r][j] - m_j[r][j]);
        if (__any(needv > 8.0f)) {
          #pragma unroll
          for (int r = 0; r < 2; ++r)
            #pragma unroll
            for (int j = 0; j < 4; ++j) {
              const float mn = fmaxf(m_j[r][j], pmax[r][j]);
              const float pf = fexp2(m_j[r][j] - mn);
              m_j[r][j] = mn;
              l_j[r][j] *= pf;
              #pragma unroll
              for (int df = 0; df < 8; ++df) o_acc[r][df][j] *= pf;
            }
        }

        // P = exp2(S - m); per-lane partial l; truncating bf16 store
        #pragma unroll
        for (int r = 0; r < 2; ++r) {
          #pragma unroll
          for (int j = 0; j < 4; ++j) {
            float lacc = 0.0f;
            #pragma unroll
            for (int kvf = 0; kvf < 4; ++kvf) {
              const float p = fexp2(sf[r][kvf][j] - m_j[r][j]);
              lacc += p;
              const int rq = r * 16 + g * 4 + j, ck = kvf * 16 + lr;
              const int ba = (rq * 128 + ck * 2) ^ ((rq & 7) << 4);
              *(u16*)((char*)&Ps[w][0] + ba) = (u16)(__builtin_bit_cast(u32, p) >> 16);
            }
            l_j[r][j] += lacc;
          }
        }

        // O += P V : V frag read ONCE, used by both row groups
        __builtin_amdgcn_s_setprio(1);
        #pragma unroll
        for (int kk = 0; kk < 2; ++kk) {
          s16x8 pf[2];
          #pragma unroll
          for (int r = 0; r < 2; ++r) {
            const int prow = r * 16 + lr;
            const int bap = (prow * 128 + kk * 64 + g * 16) ^ ((prow & 7) << 4);
            pf[r] = *(const s16x8*)((const char*)&Ps[w][0] + bap);
          }
          #pragma unroll
          for (int df = 0; df < 8; ++df) {
            const int dd = df * 16 + lr;
            const int bav = (dd * 128 + kk * 64 + g * 16) ^ ((dd & 7) << 4);
            const s16x8 vf = *(const s16x8*)((const char*)Vc + bav);
            o_acc[0][df] = __builtin_amdgcn_mfma_f32_16x16x32_bf16(pf[0], vf, o_acc[0][df], 0, 0, 0);
            o_acc[1][df] = __builtin_amdgcn_mfma_f32_16x16x32_bf16(pf[1], vf, o_acc[1][df], 0, 0, 0);
          }
        }
        __builtin_amdgcn_s_setprio(0);
      }
      cur ^= 1;
    }

    #pragma unroll
    for (int r = 0; r < 2; ++r) {
      float inv_l[4];
      #pragma unroll
      for (int j = 0; j < 4; ++j) {
        float s4 = l_j[r][j];
        s4 += __shfl_xor(s4, 1);
        s4 += __shfl_xor(s4, 2);
        s4 += __shfl_xor(s4, 4);
        s4 += __shfl_xor(s4, 8);
        inv_l[j] = 1.0f / s4;
      }
      u16* op = out + (size_t)(b * N_ + qrow0 + r * 16) * D_ + h * DH_;
      #pragma unroll
      for (int df = 0; df < 8; ++df)
        #pragma unroll
        for (int j = 0; j < 4; ++j)
          op[(size_t)(g * 4 + j) * D_ + df * 16 + lr] = f2bf(o_acc[r][df][j] * inv_l[j]);
    }
  };

  const int qlo = fi, qhi = 7 - fi;       // fold: every block runs 36 iterations
  issue(0, 0);
  run_qtile(qlo, 4 * qlo + 4, true);
  run_qtile(qhi, 4 * qhi + 4, false);
}

extern "C" void kernel_launch(void* const* d_in, const int* in_sizes, int n_in,
                              void* d_out, int out_size, void* d_ws, size_t ws_size,
                              hipStream_t stream) {
  const float* x      = (const float*)d_in[0];
  const float* normw  = (const float*)d_in[1];
  const float* qw     = (const float*)d_in[2];
  const float* qbias  = (const float*)d_in[3];
  const float* kvw    = (const float*)d_in[4];
  const float* kvbias = (const float*)d_in[5];
  const float* wow    = (const float*)d_in[6];
  const float* wob    = (const float*)d_in[7];
  // d_in[8] = kv_cache (unused: pos=0), d_in[9] = pos (0)
  float* out = (float*)d_out;

  char* ws = (char*)d_ws;
  u16* xn    = (u16*)(ws + 0);          // 33.5 MB (reused as attn output)
  u16* dq    = (u16*)(ws + 33554432);   // 33.5 MB
  u16* dkv   = (u16*)(ws + 67108864);   // 16.8 MB (V-half unused)
  u16* dvt   = (u16*)(ws + 83886080);   //  8.4 MB
  u16* wqkv  = (u16*)(ws + 92274688);   // 12.6 MB: qw bf16 [2048 rows] then kvw bf16 [1024 rows]
  u16* wowb  = (u16*)(ws + 104857600);  //  8.4 MB
  float* cost = (float*)(ws + 113246208); // 0.5 MB
  float* sint = (float*)(ws + 113770496); // 0.5 MB

  rope_tab_k<<<512, 256, 0, stream>>>(cost, sint);
  cvt_bf16_k<<<2048, 256, 0, stream>>>(qw, wqkv, 2048 * 2048);
  cvt_bf16_k<<<1024, 256, 0, stream>>>(kvw, wqkv + 2048 * 2048, 1024 * 2048);
  cvt_bf16_k<<<2048, 256, 0, stream>>>(wow, wowb, 2048 * 2048);
  rmsnorm_k<<<8192, 256, 0, stream>>>(x, normw, xn);
  gemm_p<4><<<dim3(24, 32), 512, 0, stream>>>(xn, wqkv, (void*)dq, (void*)dkv, dvt,
                                              qbias, kvbias, cost, sint);
  attn_k<<<dim3(4, 16, 4), 512, 0, stream>>>(dq, dkv, dvt, xn);
  gemm_p<0><<<dim3(16, 32), 512, 0, stream>>>(xn, wowb, (void*)out, nullptr, nullptr,
                                              wob, nullptr, nullptr, nullptr);
}